// Round 5
// baseline (37.476 us; speedup 1.0000x reference)
//
#include <hip/hip_runtime.h>

// LDDMM variational evolve: N-body Gaussian kernel sums, N=8192, D=3, fp32.
// dmom_i = (1/SIG2) * sum_j K_ij * <mom_i,mom_j> * (pos_i - pos_j)
// dpos_i = sum_j K_ij * mom_j
// K_ij = exp(-||pos_i-pos_j||^2/(2*SIG2)), SIG2=0.01 -> exp2(-72.1348*d2)
//
// d2 = ri + rj - 2<xi,xj>; LDS holds pre-scaled j-data so the exp arg is a
// pure FMA chain. Accumulate S=sum(s), SP=sum(s*xj_scaled) so
// dmom_i = 100*(xi*S - SP/A_DOT).
// exp = __builtin_amdgcn_exp2f (plain exp2f -> OCML fixup path; R2 measured).
// ILANES ladder: 2 -> 41.4us (LDS-pipe co-limit, VALUBusy 61%), 4 -> ~29us.
// ILANES=8 + THREADS=128: 2 ds_read_b128 per 120 VALU-insts, 8 indep chains
// per thread to hide v_exp latency at 2 waves/SIMD.

#define NPTS    8192
#define THREADS 128
#define ILANES  8
#define IBLK    (THREADS * ILANES)   // 1024 i's per block

#define A_DOT 144.269504088896f      // 2*50*log2(e)
#define A_R   (-72.134752044448f)    // -50*log2(e)
#define INV_SIG2 100.0f

#define EXP2(x) __builtin_amdgcn_exp2f(x)

template <int JBLK, bool ATOMIC>
__global__ __launch_bounds__(THREADS, 2)
void lddmm_main(const float* __restrict__ mom,
                const float* __restrict__ pos,
                float* __restrict__ partial,   // [NJC][6][NPTS] when !ATOMIC
                float* __restrict__ out)       // used when ATOMIC
{
    __shared__ float4 sp[JBLK];   // (A_DOT*x, A_DOT*y, A_DOT*z, A_R*r2)
    __shared__ float4 sm[JBLK];   // (mx, my, mz, 0)

    const int t  = threadIdx.x;
    const int i0 = blockIdx.x * IBLK;
    const int jc = blockIdx.y;
    const int jbase = jc * JBLK;

    if (t < JBLK) {
        const int j = jbase + t;
        const float x = pos[3*j+0], y = pos[3*j+1], z = pos[3*j+2];
        const float r2 = x*x + y*y + z*z;
        sp[t] = make_float4(A_DOT*x, A_DOT*y, A_DOT*z, A_R*r2);
        sm[t] = make_float4(mom[3*j+0], mom[3*j+1], mom[3*j+2], 0.0f);
    }
    __syncthreads();

    // Per-i registers, k = 0..ILANES-1 (all loops fully unrolled -> static idx)
    float xi[ILANES], yi[ILANES], zi[ILANES], pxi[ILANES], pyi[ILANES], pzi[ILANES], ci[ILANES];
    float S[ILANES], SPx[ILANES], SPy[ILANES], SPz[ILANES], apx[ILANES], apy[ILANES], apz[ILANES];
    #pragma unroll
    for (int k = 0; k < ILANES; ++k) {
        const int i = i0 + k * THREADS + t;
        xi[k] = pos[3*i+0]; yi[k] = pos[3*i+1]; zi[k] = pos[3*i+2];
        pxi[k] = mom[3*i+0]; pyi[k] = mom[3*i+1]; pzi[k] = mom[3*i+2];
        ci[k] = A_R * (xi[k]*xi[k] + yi[k]*yi[k] + zi[k]*zi[k]);
        S[k]=0.f; SPx[k]=0.f; SPy[k]=0.f; SPz[k]=0.f; apx[k]=0.f; apy[k]=0.f; apz[k]=0.f;
    }

    #pragma unroll 2
    for (int j = 0; j < JBLK; ++j) {
        const float4 P = sp[j];   // broadcast ds_read_b128
        const float4 M = sm[j];
        #pragma unroll
        for (int k = 0; k < ILANES; ++k) {
            float arg = __builtin_fmaf(xi[k], P.x, ci[k] + P.w);
            arg = __builtin_fmaf(yi[k], P.y, arg);
            arg = __builtin_fmaf(zi[k], P.z, arg);
            const float K = EXP2(arg);
            const float C = __builtin_fmaf(pzi[k], M.z,
                              __builtin_fmaf(pyi[k], M.y, pxi[k]*M.x));
            const float s = K * C;
            S[k]  += s;
            SPx[k] = __builtin_fmaf(s, P.x, SPx[k]);
            SPy[k] = __builtin_fmaf(s, P.y, SPy[k]);
            SPz[k] = __builtin_fmaf(s, P.z, SPz[k]);
            apx[k] = __builtin_fmaf(K, M.x, apx[k]);
            apy[k] = __builtin_fmaf(K, M.y, apy[k]);
            apz[k] = __builtin_fmaf(K, M.z, apz[k]);
        }
    }

    const float US = INV_SIG2 / A_DOT;
    #pragma unroll
    for (int k = 0; k < ILANES; ++k) {
        const int i = i0 + k * THREADS + t;
        const float amx = INV_SIG2*xi[k]*S[k] - US*SPx[k];
        const float amy = INV_SIG2*yi[k]*S[k] - US*SPy[k];
        const float amz = INV_SIG2*zi[k]*S[k] - US*SPz[k];
        if (!ATOMIC) {
            float* base = partial + (size_t)jc * (6 * NPTS);
            base[0*NPTS + i] = amx;
            base[1*NPTS + i] = amy;
            base[2*NPTS + i] = amz;
            base[3*NPTS + i] = apx[k];
            base[4*NPTS + i] = apy[k];
            base[5*NPTS + i] = apz[k];
        } else {
            atomicAdd(&out[3*i+0], amx);
            atomicAdd(&out[3*i+1], amy);
            atomicAdd(&out[3*i+2], amz);
            atomicAdd(&out[3*NPTS + 3*i+0], apx[k]);
            atomicAdd(&out[3*NPTS + 3*i+1], apy[k]);
            atomicAdd(&out[3*NPTS + 3*i+2], apz[k]);
        }
    }
}

// Coalesced reduce over planar partials: thread handles 4 consecutive planar
// slots (comp,i) with i fastest -> float4 reads are contiguous per jc-plane.
template <int NJC>
__global__ __launch_bounds__(256)
void lddmm_reduce(const float* __restrict__ partial, float* __restrict__ out)
{
    const int p0 = (blockIdx.x * 256 + threadIdx.x) * 4;  // 0 .. 6*NPTS-1, step 4
    float4 s = make_float4(0.f, 0.f, 0.f, 0.f);
    #pragma unroll
    for (int jc = 0; jc < NJC; ++jc) {
        const float4 v = *reinterpret_cast<const float4*>(
            partial + (size_t)jc * (6 * NPTS) + p0);
        s.x += v.x; s.y += v.y; s.z += v.z; s.w += v.w;
    }
    const int comp = p0 / NPTS;        // constant across the 4 (NPTS % 4 == 0)
    const int i0   = p0 % NPTS;
    const int base = (comp < 3) ? 0 : 3 * NPTS;
    const int c    = (comp < 3) ? comp : comp - 3;
    const float sv[4] = {s.x, s.y, s.z, s.w};
    #pragma unroll
    for (int k = 0; k < 4; ++k)
        out[base + 3 * (i0 + k) + c] = sv[k];
}

extern "C" void kernel_launch(void* const* d_in, const int* in_sizes, int n_in,
                              void* d_out, int out_size, void* d_ws, size_t ws_size,
                              hipStream_t stream)
{
    const float* mom = (const float*)d_in[0];
    const float* pos = (const float*)d_in[1];
    float* out = (float*)d_out;
    float* partial = (float*)d_ws;

    const size_t per_jc = (size_t)6 * NPTS * sizeof(float);  // 196608 B
    const int rblocks = (6 * NPTS) / (256 * 4);              // 48

    if (ws_size >= 128 * per_jc) {
        // JBLK=64, NJC=128 -> grid 8x128 = 1024 blocks = 4 blocks/CU
        dim3 grid(NPTS / IBLK, 128);
        lddmm_main<64, false><<<grid, THREADS, 0, stream>>>(mom, pos, partial, out);
        lddmm_reduce<128><<<rblocks, 256, 0, stream>>>(partial, out);
    } else if (ws_size >= 64 * per_jc) {
        dim3 grid(NPTS / IBLK, 64);
        lddmm_main<128, false><<<grid, THREADS, 0, stream>>>(mom, pos, partial, out);
        lddmm_reduce<64><<<rblocks, 256, 0, stream>>>(partial, out);
    } else if (ws_size >= 32 * per_jc) {
        dim3 grid(NPTS / IBLK, 32);
        lddmm_main<256, false><<<grid, THREADS, 0, stream>>>(mom, pos, partial, out);
        lddmm_reduce<32><<<rblocks, 256, 0, stream>>>(partial, out);
    } else {
        hipMemsetAsync(out, 0, (size_t)6 * NPTS * sizeof(float), stream);
        dim3 grid(NPTS / IBLK, 32);
        lddmm_main<256, true><<<grid, THREADS, 0, stream>>>(mom, pos, nullptr, out);
    }
}